// Round 12
// baseline (558.238 us; speedup 1.0000x reference)
//
#include <hip/hip_runtime.h>

#define NPTS 4096
#define CH 64
#define BATCH 8
#define KNN 20
#define NEG_SLOPE 0.2f
#define EPSV 1e-5f
#define NEG_INF (-3.4e38f)

typedef float v2f __attribute__((ext_vector_type(2)));

// ---------------- K0: xx[b,n] = sum_c x[b,c,n]^2 ----------------
__global__ void k_xx(const float* __restrict__ x, float* __restrict__ xx) {
  int t = blockIdx.x * 256 + threadIdx.x;          // [0, B*N)
  int b = t >> 12, n = t & (NPTS - 1);
  const float* xp = x + ((size_t)b * CH * NPTS) + n;
  float s = 0.f;
#pragma unroll
  for (int c = 0; c < CH; ++c) { float v = xp[(size_t)c * NPTS]; s = fmaf(v, v, s); }
  xx[t] = s;
}

// ---------------- K2: P'[t,o], Q'[t,o] ----------------
__global__ void k_pq(const float* __restrict__ x, const float* __restrict__ W,
                     const float* __restrict__ gamma, const float* __restrict__ beta,
                     const float* __restrict__ rmean, const float* __restrict__ rvar,
                     float* __restrict__ P, float* __restrict__ Q) {
  __shared__ float Ws1[CH * CH];   // [c][o], W1*inv
  __shared__ float Wsd[CH * CH];   // [c][o], (W2-W1)*inv
  int tid = threadIdx.x;
  for (int i = tid; i < CH * CH; i += 256) {
    int o = i & 63, c = i >> 6;
    float s = gamma[o] * rsqrtf(rvar[o] + EPSV);
    float w1 = W[o * 128 + c], w2 = W[o * 128 + 64 + c];
    Ws1[c * 64 + o] = w1 * s;
    Wsd[c * 64 + o] = (w2 - w1) * s;
  }
  __syncthreads();
  int o = tid & 63, ng = tid >> 6;
  float s = gamma[o] * rsqrtf(rvar[o] + EPSV);
  float shift = beta[o] - rmean[o] * s;
  int base = blockIdx.x * 16;
  for (int rp = 0; rp < 4; ++rp) {
    int t = base + rp * 4 + ng;                    // row in [0, B*N)
    int b = t >> 12, n = t & (NPTS - 1);
    const float* xp = x + ((size_t)b * CH * NPTS) + n;
    float accp = 0.f, accq = 0.f;
#pragma unroll 8
    for (int c = 0; c < CH; ++c) {
      float xv = xp[(size_t)c * NPTS];
      accp = fmaf(xv, Ws1[c * 64 + o], accp);
      accq = fmaf(xv, Wsd[c * 64 + o], accq);
    }
    P[(size_t)t * 64 + o] = accp;
    Q[(size_t)t * 64 + o] = accq + shift;
  }
}

// ---------------- K1 helpers ----------------
// packed fp32 fma: element-wise IEEE fma -> bit-identical to scalar chain
__device__ __forceinline__ v2f fma2(float a, v2f b, v2f c) {
#if __has_builtin(__builtin_elementwise_fma)
  v2f av; av.x = a; av.y = a;
  return __builtin_elementwise_fma(av, b, c);
#else
  v2f r; r.x = fmaf(a, b.x, c.x); r.y = fmaf(a, b.y, c.y); return r;
#endif
}

// ballot-gated serial insert with in-loop threshold tightening (R5-R11, passed).
__device__ __forceinline__ void insert_group(float d, int mg, int lane,
                                             float& vr, int& ir, float& th) {
  unsigned long long hit = __ballot(d > th);
  while (hit) {
    int j = __builtin_ctzll(hit);
    hit &= hit - 1;
    float cv = __shfl(d, j);
    int cm = mg + j;
    unsigned long long km = __ballot(vr >= cv);    // existing equals stay above
    int cnt = __popcll(km);
    float sv = __shfl_up(vr, 1);
    int si = __shfl_up(ir, 1);
    if (lane >= cnt) {
      vr = (lane == cnt) ? cv : sv;
      ir = (lane == cnt) ? cm : si;
    }
    th = __shfl(vr, KNN - 1);                      // refreshed 20th-best
    if (hit) hit &= __ballot(d > th);              // prune sub-threshold hits
  }
}

// bitonic seed sort (R5-R11, passed): 64 (d, col=lane) pairs, d desc, ties ->
// lower col. Equals serial insertion into the empty list -> bit-identical.
__device__ __forceinline__ void seed_sort(float d, int lane,
                                          float& vr, int& ir, float& th) {
  float v = d; int ix = lane;
#pragma unroll
  for (int k = 2; k <= 64; k <<= 1) {
#pragma unroll
    for (int j = k >> 1; j > 0; j >>= 1) {
      float pv = __shfl_xor(v, j);
      int   pi = __shfl_xor(ix, j);
      bool lower = (lane & j) == 0;
      bool desc  = (lane & k) == 0;                // block direction
      bool mineBefore = (v > pv) || (v == pv && ix < pi);
      bool keep = (mineBefore == (lower == desc));
      v  = keep ? v  : pv;
      ix = keep ? ix : pi;
    }
  }
  vr = v; ir = ix; th = __shfl(v, KNN - 1);
}

// GEMM (8 rows x 8 cols per thread; lane==col within each 64-group) +
// register-direct selection. R11 geometry (passed, best at 380us) with the
// register budget FIXED: R11's launch_bounds(1024,4) led the compiler to a
// 64-VGPR allocation (targeting 8 waves/EU the 1-block/CU grid never gets),
// spilling the 64-reg acc array in the hot loop (WRITE_SIZE 2.5->9.7MB).
// waves_per_eu(4,4) pins the target to the real occupancy -> 128-reg budget.
// Candidate order: chunks ascending, groups g=0..7 ascending, ctz within
// group = global ascending column order -> bit-identical output.
template <bool SEED>
__device__ __forceinline__ void tile_work(const float* __restrict__ bp,
                                          const float* As,
                                          const float* xxb, int m0, int w, int lane,
                                          const float (&xnr)[8],
                                          float (&val)[8], int (&idx)[8],
                                          float (&thd)[8]) {
  float xm[8];
#pragma unroll
  for (int g = 0; g < 8; ++g) xm[g] = xxb[m0 + 64 * g + lane];

  const float* Aw = As + 8 * w;                    // rows 8w..8w+7, LDA=128
  const float* bc = bp + m0;                       // per-lane: col m0+lane

  v2f acc[8][4];                                   // [row][col-pair]
#pragma unroll
  for (int r = 0; r < 8; ++r)
#pragma unroll
    for (int gp = 0; gp < 4; ++gp) { acc[r][gp].x = 0.f; acc[r][gp].y = 0.f; }

#pragma unroll 4
  for (int c = 0; c < CH; ++c) {
    float4 A0 = *(const float4*)(Aw + c * 128);      // rows 8w..8w+3 (broadcast)
    float4 A1 = *(const float4*)(Aw + c * 128 + 4);  // rows 8w+4..8w+7
    const float* bcc = bc + (size_t)c * NPTS;
    v2f bb[4];
    bb[0].x = bcc[0];    bb[0].y = bcc[64];          // cols m0+{0,64}+lane
    bb[1].x = bcc[128];  bb[1].y = bcc[192];
    bb[2].x = bcc[256];  bb[2].y = bcc[320];
    bb[3].x = bcc[384];  bb[3].y = bcc[448];
    float av[8] = {A0.x, A0.y, A0.z, A0.w, A1.x, A1.y, A1.z, A1.w};
#pragma unroll
    for (int r = 0; r < 8; ++r)
#pragma unroll
      for (int gp = 0; gp < 4; ++gp)
        acc[r][gp] = fma2(av[r], bb[gp], acc[r][gp]);
  }

#pragma unroll
  for (int r = 0; r < 8; ++r) {
#pragma unroll
    for (int gp = 0; gp < 4; ++gp) {
      float d0 = (2.f * acc[r][gp].x - xnr[r]) - xm[2 * gp];
      if (SEED && gp == 0) {
        seed_sort(d0, lane, val[r], idx[r], thd[r]);  // m0==0, g==0: col==lane
      } else {
        insert_group(d0, m0 + 128 * gp, lane, val[r], idx[r], thd[r]);
      }
      float d1 = (2.f * acc[r][gp].y - xnr[r]) - xm[2 * gp + 1];
      insert_group(d1, m0 + 128 * gp + 64, lane, val[r], idx[r], thd[r]);
    }
  }
}

// ---------------- K1: fused distance-GEMM + register-direct top-20 ----------
// 1024 threads = 16 waves = 4 waves/SIMD; wave w owns rows 8w..8w+7;
// 128 rows/block, m-chunks of 512 cols (8 chunks). LDS = As 32KB only.
// No per-tile barriers; B from L2 (XCD swizzle b=bid&7 keeps each batch's
// 1MB x on one XCD's L2). 1024-thr blocks hardware-require VGPR<=128;
// waves_per_eu(4,4) stops the compiler's 64-reg/8-wave squeeze (R11 spill).
__global__ void __launch_bounds__(1024)
__attribute__((amdgpu_waves_per_eu(4, 4)))
k_knn(const float* __restrict__ x, const float* __restrict__ xx,
      int* __restrict__ idxout) {
  __shared__ float As[64 * 128];                   // [c][n], LDA=128
  int tid = threadIdx.x;
  int bid = blockIdx.x;
  int b = bid & 7, nb = bid >> 3;                  // XCD-swizzled decode
  int n0 = nb * 128;
  const float* xb = x + (size_t)b * CH * NPTS;
  const float* xxb = xx + b * NPTS;
  int lane = tid & 63;
  int w = tid >> 6;                                // 0..15

  // stage A-tile [c][n]: 8192 floats, 1024 threads x 8 floats
  {
    int c = tid >> 4, n8 = (tid & 15) << 3;
    float4 v0 = *(const float4*)(xb + (size_t)c * NPTS + n0 + n8);
    float4 v1 = *(const float4*)(xb + (size_t)c * NPTS + n0 + n8 + 4);
    *(float4*)(As + c * 128 + n8) = v0;
    *(float4*)(As + c * 128 + n8 + 4) = v1;
  }

  float xnr[8];
#pragma unroll
  for (int r = 0; r < 8; ++r) xnr[r] = xxb[n0 + 8 * w + r];

  float val[8]; int idx[8]; float thd[8];
#pragma unroll
  for (int r = 0; r < 8; ++r) { val[r] = NEG_INF; idx[r] = 0; thd[r] = NEG_INF; }

  __syncthreads();                                 // As ready (the ONLY barrier)

  const float* bp = xb + lane;                     // per-lane B base

  // chunk 0: seeded selection
  tile_work<true>(bp, As, xxb, 0, w, lane, xnr, val, idx, thd);

#pragma unroll 1
  for (int mt = 1; mt < NPTS / 512; ++mt)
    tile_work<false>(bp, As, xxb, mt * 512, w, lane, xnr, val, idx, thd);

  // emit: lane l (<20) holds l-th best index for row 8w+r
#pragma unroll
  for (int r = 0; r < 8; ++r) {
    int n = n0 + 8 * w + r;
    if (lane < KNN) idxout[(size_t)(b * NPTS + n) * KNN + lane] = idx[r];
  }
}

// ---------------- K3: gather + max + leaky, transpose to (B,O,N) ----------------
__global__ void k_out(const float* __restrict__ P, const float* __restrict__ Q,
                      const int* __restrict__ idx, float* __restrict__ out) {
  __shared__ float T[64 * 65];
  int tid = threadIdx.x;
  int nb = blockIdx.x, b = blockIdx.y;
  int n0 = nb * 64;
  int o = tid & 63, ng = tid >> 6;
  const float* Pb = P + (size_t)b * NPTS * 64;
  for (int p = 0; p < 16; ++p) {
    int nl = p * 4 + ng;
    int n = n0 + nl;
    const int* ip = idx + (size_t)(b * NPTS + n) * KNN;
    float mx = NEG_INF;
#pragma unroll
    for (int k = 0; k < KNN; ++k) {
      int id = ip[k];
      float v = Pb[(size_t)id * 64 + o];
      mx = fmaxf(mx, v);
    }
    float z = mx + Q[(size_t)(b * NPTS + n) * 64 + o];
    z = (z >= 0.f) ? z : NEG_SLOPE * z;
    T[o * 65 + nl] = z;
  }
  __syncthreads();
  float* ob = out + (size_t)b * 64 * NPTS + n0;
  int nl = tid & 63;
  for (int w = 0; w < 16; ++w) {
    int oo = w * 4 + ng;
    ob[(size_t)oo * NPTS + nl] = T[oo * 65 + nl];
  }
}

extern "C" void kernel_launch(void* const* d_in, const int* in_sizes, int n_in,
                              void* d_out, int out_size, void* d_ws, size_t ws_size,
                              hipStream_t stream) {
  const float* x     = (const float*)d_in[0];
  const float* W     = (const float*)d_in[1];
  const float* gamma = (const float*)d_in[2];
  const float* beta  = (const float*)d_in[3];
  const float* rmean = (const float*)d_in[4];
  const float* rvar  = (const float*)d_in[5];
  float* out = (float*)d_out;

  float* xx = (float*)d_ws;                        // 32768 floats
  float* P  = xx + 32768;                          // 2097152 floats
  float* Q  = P + 2097152;                         // 2097152 floats
  int*   idx = (int*)(Q + 2097152);                // 655360 ints

  k_xx<<<BATCH * NPTS / 256, 256, 0, stream>>>(x, xx);
  k_pq<<<BATCH * NPTS / 16, 256, 0, stream>>>(x, W, gamma, beta, rmean, rvar, P, Q);
  k_knn<<<BATCH * NPTS / 128, 1024, 0, stream>>>(x, xx, idx);
  k_out<<<dim3(NPTS / 64, BATCH), 256, 0, stream>>>(P, Q, idx, out);
}

// Round 13
// 508.204 us; speedup vs baseline: 1.0985x; 1.0985x over previous
//
#include <hip/hip_runtime.h>

#define NPTS 4096
#define CH 64
#define BATCH 8
#define KNN 20
#define NEG_SLOPE 0.2f
#define EPSV 1e-5f
#define NEG_INF (-3.4e38f)

typedef float v2f __attribute__((ext_vector_type(2)));

// ---------------- K0: xx[b,n] = sum_c x[b,c,n]^2 ----------------
__global__ void k_xx(const float* __restrict__ x, float* __restrict__ xx) {
  int t = blockIdx.x * 256 + threadIdx.x;          // [0, B*N)
  int b = t >> 12, n = t & (NPTS - 1);
  const float* xp = x + ((size_t)b * CH * NPTS) + n;
  float s = 0.f;
#pragma unroll
  for (int c = 0; c < CH; ++c) { float v = xp[(size_t)c * NPTS]; s = fmaf(v, v, s); }
  xx[t] = s;
}

// ---------------- K2: P'[t,o], Q'[t,o] ----------------
__global__ void k_pq(const float* __restrict__ x, const float* __restrict__ W,
                     const float* __restrict__ gamma, const float* __restrict__ beta,
                     const float* __restrict__ rmean, const float* __restrict__ rvar,
                     float* __restrict__ P, float* __restrict__ Q) {
  __shared__ float Ws1[CH * CH];   // [c][o], W1*inv
  __shared__ float Wsd[CH * CH];   // [c][o], (W2-W1)*inv
  int tid = threadIdx.x;
  for (int i = tid; i < CH * CH; i += 256) {
    int o = i & 63, c = i >> 6;
    float s = gamma[o] * rsqrtf(rvar[o] + EPSV);
    float w1 = W[o * 128 + c], w2 = W[o * 128 + 64 + c];
    Ws1[c * 64 + o] = w1 * s;
    Wsd[c * 64 + o] = (w2 - w1) * s;
  }
  __syncthreads();
  int o = tid & 63, ng = tid >> 6;
  float s = gamma[o] * rsqrtf(rvar[o] + EPSV);
  float shift = beta[o] - rmean[o] * s;
  int base = blockIdx.x * 16;
  for (int rp = 0; rp < 4; ++rp) {
    int t = base + rp * 4 + ng;                    // row in [0, B*N)
    int b = t >> 12, n = t & (NPTS - 1);
    const float* xp = x + ((size_t)b * CH * NPTS) + n;
    float accp = 0.f, accq = 0.f;
#pragma unroll 8
    for (int c = 0; c < CH; ++c) {
      float xv = xp[(size_t)c * NPTS];
      accp = fmaf(xv, Ws1[c * 64 + o], accp);
      accq = fmaf(xv, Wsd[c * 64 + o], accq);
    }
    P[(size_t)t * 64 + o] = accp;
    Q[(size_t)t * 64 + o] = accq + shift;
  }
}

// ---------------- K1 helpers ----------------
// packed fp32 fma: element-wise IEEE fma -> bit-identical to scalar chain
__device__ __forceinline__ v2f fma2(float a, v2f b, v2f c) {
#if __has_builtin(__builtin_elementwise_fma)
  v2f av; av.x = a; av.y = a;
  return __builtin_elementwise_fma(av, b, c);
#else
  v2f r; r.x = fmaf(a, b.x, c.x); r.y = fmaf(a, b.y, c.y); return r;
#endif
}

// ballot-gated serial insert with in-loop threshold tightening (R5-R12, passed).
__device__ __forceinline__ void insert_group(float d, int mg, int lane,
                                             float& vr, int& ir, float& th) {
  unsigned long long hit = __ballot(d > th);
  while (hit) {
    int j = __builtin_ctzll(hit);
    hit &= hit - 1;
    float cv = __shfl(d, j);
    int cm = mg + j;
    unsigned long long km = __ballot(vr >= cv);    // existing equals stay above
    int cnt = __popcll(km);
    float sv = __shfl_up(vr, 1);
    int si = __shfl_up(ir, 1);
    if (lane >= cnt) {
      vr = (lane == cnt) ? cv : sv;
      ir = (lane == cnt) ? cm : si;
    }
    th = __shfl(vr, KNN - 1);                      // refreshed 20th-best
    if (hit) hit &= __ballot(d > th);              // prune sub-threshold hits
  }
}

// bitonic seed sort (R5-R12, passed): 64 (d, col=lane) pairs, d desc, ties ->
// lower col. Equals serial insertion into the empty list -> bit-identical.
__device__ __forceinline__ void seed_sort(float d, int lane,
                                          float& vr, int& ir, float& th) {
  float v = d; int ix = lane;
#pragma unroll
  for (int k = 2; k <= 64; k <<= 1) {
#pragma unroll
    for (int j = k >> 1; j > 0; j >>= 1) {
      float pv = __shfl_xor(v, j);
      int   pi = __shfl_xor(ix, j);
      bool lower = (lane & j) == 0;
      bool desc  = (lane & k) == 0;                // block direction
      bool mineBefore = (v > pv) || (v == pv && ix < pi);
      bool keep = (mineBefore == (lower == desc));
      v  = keep ? v  : pv;
      ix = keep ? ix : pi;
    }
  }
  vr = v; ir = ix; th = __shfl(v, KNN - 1);
}

// GEMM (8 rows x 8 cols per thread; lane==col within each 64-group) +
// register-direct selection. R11's exact geometry/math (best, 380us).
// Candidate order: chunks ascending, groups g=0..7 ascending, ctz within
// group = global ascending column order -> bit-identical output.
template <bool SEED>
__device__ __forceinline__ void tile_work(const float* __restrict__ bp,
                                          const float* As,
                                          const float* xxb, int m0, int w, int lane,
                                          const float (&xnr)[8],
                                          float (&val)[8], int (&idx)[8],
                                          float (&thd)[8]) {
  float xm[8];
#pragma unroll
  for (int g = 0; g < 8; ++g) xm[g] = xxb[m0 + 64 * g + lane];

  const float* Aw = As + 8 * w;                    // rows 8w..8w+7, LDA=64
  const float* bc = bp + m0;                       // per-lane: col m0+lane

  v2f acc[8][4];                                   // [row][col-pair] = 64 VGPR
#pragma unroll
  for (int r = 0; r < 8; ++r)
#pragma unroll
    for (int gp = 0; gp < 4; ++gp) { acc[r][gp].x = 0.f; acc[r][gp].y = 0.f; }

#pragma unroll 2
  for (int c = 0; c < CH; ++c) {
    float4 A0 = *(const float4*)(Aw + c * 64);       // rows 8w..8w+3 (broadcast)
    float4 A1 = *(const float4*)(Aw + c * 64 + 4);   // rows 8w+4..8w+7
    const float* bcc = bc + (size_t)c * NPTS;
    v2f bb[4];
    bb[0].x = bcc[0];    bb[0].y = bcc[64];          // cols m0+{0,64}+lane
    bb[1].x = bcc[128];  bb[1].y = bcc[192];
    bb[2].x = bcc[256];  bb[2].y = bcc[320];
    bb[3].x = bcc[384];  bb[3].y = bcc[448];
    float av[8] = {A0.x, A0.y, A0.z, A0.w, A1.x, A1.y, A1.z, A1.w};
#pragma unroll
    for (int r = 0; r < 8; ++r)
#pragma unroll
      for (int gp = 0; gp < 4; ++gp)
        acc[r][gp] = fma2(av[r], bb[gp], acc[r][gp]);
  }

#pragma unroll
  for (int r = 0; r < 8; ++r) {
#pragma unroll
    for (int gp = 0; gp < 4; ++gp) {
      float d0 = (2.f * acc[r][gp].x - xnr[r]) - xm[2 * gp];
      if (SEED && gp == 0) {
        seed_sort(d0, lane, val[r], idx[r], thd[r]);  // m0==0, g==0: col==lane
      } else {
        insert_group(d0, m0 + 128 * gp, lane, val[r], idx[r], thd[r]);
      }
      float d1 = (2.f * acc[r][gp].y - xnr[r]) - xm[2 * gp + 1];
      insert_group(d1, m0 + 128 * gp + 64, lane, val[r], idx[r], thd[r]);
    }
  }
}

// ---------------- K1: fused distance-GEMM + register-direct top-20 ----------
// 512 threads = 8 waves; wave w owns rows 8w..8w+7; 64 rows/block.
// Grid = 512 blocks = 2 blocks/CU -> 16 waves/CU = 4 waves/SIMD (same
// residency as R11) but VGPR budget now set STRUCTURALLY by
// __launch_bounds__(512, 4): 4 waves/EU -> 128-reg allocation. R10 proved
// the 2nd arg is the one knob the allocator honors; R11/R12's 64-reg
// squeeze (acc array spilled, WRITE_SIZE 9.7->175MB) is lifted.
// LDS = As[64][64] 16KB only; B from L2 (XCD swizzle b=bid&7); one barrier.
__launch_bounds__(512, 4)
__global__ void k_knn(const float* __restrict__ x, const float* __restrict__ xx,
                      int* __restrict__ idxout) {
  __shared__ float As[64 * 64];                    // [c][n], LDA=64
  int tid = threadIdx.x;
  int bid = blockIdx.x;
  int b = bid & 7, nb = bid >> 3;                  // XCD-swizzled decode
  int n0 = nb * 64;
  const float* xb = x + (size_t)b * CH * NPTS;
  const float* xxb = xx + b * NPTS;
  int lane = tid & 63;
  int w = tid >> 6;                                // 0..7

  // stage A-tile [c][n]: 4096 floats, 512 threads x 8 floats
  {
    int c = tid >> 3, n8 = (tid & 7) << 3;
    float4 v0 = *(const float4*)(xb + (size_t)c * NPTS + n0 + n8);
    float4 v1 = *(const float4*)(xb + (size_t)c * NPTS + n0 + n8 + 4);
    *(float4*)(As + c * 64 + n8) = v0;
    *(float4*)(As + c * 64 + n8 + 4) = v1;
  }

  float xnr[8];
#pragma unroll
  for (int r = 0; r < 8; ++r) xnr[r] = xxb[n0 + 8 * w + r];

  float val[8]; int idx[8]; float thd[8];
#pragma unroll
  for (int r = 0; r < 8; ++r) { val[r] = NEG_INF; idx[r] = 0; thd[r] = NEG_INF; }

  __syncthreads();                                 // As ready (the ONLY barrier)

  const float* bp = xb + lane;                     // per-lane B base

  // chunk 0: seeded selection
  tile_work<true>(bp, As, xxb, 0, w, lane, xnr, val, idx, thd);

#pragma unroll 1
  for (int mt = 1; mt < NPTS / 512; ++mt)
    tile_work<false>(bp, As, xxb, mt * 512, w, lane, xnr, val, idx, thd);

  // emit: lane l (<20) holds l-th best index for row 8w+r
#pragma unroll
  for (int r = 0; r < 8; ++r) {
    int n = n0 + 8 * w + r;
    if (lane < KNN) idxout[(size_t)(b * NPTS + n) * KNN + lane] = idx[r];
  }
}

// ---------------- K3: gather + max + leaky, transpose to (B,O,N) ----------------
__global__ void k_out(const float* __restrict__ P, const float* __restrict__ Q,
                      const int* __restrict__ idx, float* __restrict__ out) {
  __shared__ float T[64 * 65];
  int tid = threadIdx.x;
  int nb = blockIdx.x, b = blockIdx.y;
  int n0 = nb * 64;
  int o = tid & 63, ng = tid >> 6;
  const float* Pb = P + (size_t)b * NPTS * 64;
  for (int p = 0; p < 16; ++p) {
    int nl = p * 4 + ng;
    int n = n0 + nl;
    const int* ip = idx + (size_t)(b * NPTS + n) * KNN;
    float mx = NEG_INF;
#pragma unroll
    for (int k = 0; k < KNN; ++k) {
      int id = ip[k];
      float v = Pb[(size_t)id * 64 + o];
      mx = fmaxf(mx, v);
    }
    float z = mx + Q[(size_t)(b * NPTS + n) * 64 + o];
    z = (z >= 0.f) ? z : NEG_SLOPE * z;
    T[o * 65 + nl] = z;
  }
  __syncthreads();
  float* ob = out + (size_t)b * 64 * NPTS + n0;
  int nl = tid & 63;
  for (int w = 0; w < 16; ++w) {
    int oo = w * 4 + ng;
    ob[(size_t)oo * NPTS + nl] = T[oo * 65 + nl];
  }
}

extern "C" void kernel_launch(void* const* d_in, const int* in_sizes, int n_in,
                              void* d_out, int out_size, void* d_ws, size_t ws_size,
                              hipStream_t stream) {
  const float* x     = (const float*)d_in[0];
  const float* W     = (const float*)d_in[1];
  const float* gamma = (const float*)d_in[2];
  const float* beta  = (const float*)d_in[3];
  const float* rmean = (const float*)d_in[4];
  const float* rvar  = (const float*)d_in[5];
  float* out = (float*)d_out;

  float* xx = (float*)d_ws;                        // 32768 floats
  float* P  = xx + 32768;                          // 2097152 floats
  float* Q  = P + 2097152;                         // 2097152 floats
  int*   idx = (int*)(Q + 2097152);                // 655360 ints

  k_xx<<<BATCH * NPTS / 256, 256, 0, stream>>>(x, xx);
  k_pq<<<BATCH * NPTS / 16, 256, 0, stream>>>(x, W, gamma, beta, rmean, rvar, P, Q);
  k_knn<<<BATCH * NPTS / 64, 512, 0, stream>>>(x, xx, idx);
  k_out<<<dim3(NPTS / 64, BATCH), 256, 0, stream>>>(P, Q, idx, out);
}

// Round 14
// 499.475 us; speedup vs baseline: 1.1176x; 1.0175x over previous
//
#include <hip/hip_runtime.h>

#define NPTS 4096
#define CH 64
#define BATCH 8
#define KNN 20
#define NEG_SLOPE 0.2f
#define EPSV 1e-5f
#define NEG_INF (-3.4e38f)

typedef float v2f __attribute__((ext_vector_type(2)));

// ---------------- K2: P'[t,o], Q'[t,o], and xx (fused k_xx) ----------------
__global__ void k_pq(const float* __restrict__ x, const float* __restrict__ W,
                     const float* __restrict__ gamma, const float* __restrict__ beta,
                     const float* __restrict__ rmean, const float* __restrict__ rvar,
                     float* __restrict__ P, float* __restrict__ Q,
                     float* __restrict__ xx) {
  __shared__ float Ws1[CH * CH];   // [c][o], W1*inv
  __shared__ float Wsd[CH * CH];   // [c][o], (W2-W1)*inv
  int tid = threadIdx.x;
  for (int i = tid; i < CH * CH; i += 256) {
    int o = i & 63, c = i >> 6;
    float s = gamma[o] * rsqrtf(rvar[o] + EPSV);
    float w1 = W[o * 128 + c], w2 = W[o * 128 + 64 + c];
    Ws1[c * 64 + o] = w1 * s;
    Wsd[c * 64 + o] = (w2 - w1) * s;
  }
  __syncthreads();
  int o = tid & 63, ng = tid >> 6;
  float s = gamma[o] * rsqrtf(rvar[o] + EPSV);
  float shift = beta[o] - rmean[o] * s;
  int base = blockIdx.x * 16;
  for (int rp = 0; rp < 4; ++rp) {
    int t = base + rp * 4 + ng;                    // row in [0, B*N)
    int b = t >> 12, n = t & (NPTS - 1);
    const float* xp = x + ((size_t)b * CH * NPTS) + n;
    float accp = 0.f, accq = 0.f, accx = 0.f;
#pragma unroll 8
    for (int c = 0; c < CH; ++c) {
      float xv = xp[(size_t)c * NPTS];
      accp = fmaf(xv, Ws1[c * 64 + o], accp);
      accq = fmaf(xv, Wsd[c * 64 + o], accq);
      accx = fmaf(xv, xv, accx);                   // same chain as old k_xx
    }
    P[(size_t)t * 64 + o] = accp;
    Q[(size_t)t * 64 + o] = accq + shift;
    if (o == 0) ; // (no-op; xx written by lane 0 of each o-group below)
    if ((tid & 63) == 0) ; // keep structure simple: one writer per t
    if (o == 0) xx[t] = accx;                      // o==0 thread owns row t
  }
}

// ---------------- K1 helpers ----------------
// forced v_pk_fma_f32: processes TWO output rows (lo/hi of the A pair)
// against one B column-pair. op_sel broadcasts the selected 32-bit half of
// S0 to BOTH result lanes -> no duplication movs. Each lane is an IEEE fma
// -> bit-identical to the scalar fmaf chain. Register-only asm (schedulable,
// no memory/counters).
__device__ __forceinline__ void fma2pair(v2f ap, v2f b, v2f& aclo, v2f& achi) {
  asm("v_pk_fma_f32 %0, %1, %2, %0 op_sel:[0,0,0] op_sel_hi:[0,1,1]"
      : "+v"(aclo) : "v"(ap), "v"(b));             // rows lo: both lanes ap.lo
  asm("v_pk_fma_f32 %0, %1, %2, %0 op_sel:[1,0,0] op_sel_hi:[1,1,1]"
      : "+v"(achi) : "v"(ap), "v"(b));             // rows hi: both lanes ap.hi
}

// ballot-gated serial insert with in-loop threshold tightening (R5-R13, passed).
__device__ __forceinline__ void insert_group(float d, int mg, int lane,
                                             float& vr, int& ir, float& th) {
  unsigned long long hit = __ballot(d > th);
  while (hit) {
    int j = __builtin_ctzll(hit);
    hit &= hit - 1;
    float cv = __shfl(d, j);
    int cm = mg + j;
    unsigned long long km = __ballot(vr >= cv);    // existing equals stay above
    int cnt = __popcll(km);
    float sv = __shfl_up(vr, 1);
    int si = __shfl_up(ir, 1);
    if (lane >= cnt) {
      vr = (lane == cnt) ? cv : sv;
      ir = (lane == cnt) ? cm : si;
    }
    th = __shfl(vr, KNN - 1);                      // refreshed 20th-best
    if (hit) hit &= __ballot(d > th);              // prune sub-threshold hits
  }
}

// bitonic seed sort (R5-R13, passed): 64 (d, col=lane) pairs, d desc, ties ->
// lower col. Equals serial insertion into the empty list -> bit-identical.
__device__ __forceinline__ void seed_sort(float d, int lane,
                                          float& vr, int& ir, float& th) {
  float v = d; int ix = lane;
#pragma unroll
  for (int k = 2; k <= 64; k <<= 1) {
#pragma unroll
    for (int j = k >> 1; j > 0; j >>= 1) {
      float pv = __shfl_xor(v, j);
      int   pi = __shfl_xor(ix, j);
      bool lower = (lane & j) == 0;
      bool desc  = (lane & k) == 0;                // block direction
      bool mineBefore = (v > pv) || (v == pv && ix < pi);
      bool keep = (mineBefore == (lower == desc));
      v  = keep ? v  : pv;
      ix = keep ? ix : pi;
    }
  }
  vr = v; ir = ix; th = __shfl(v, KNN - 1);
}

// GEMM (8 rows x 8 cols per thread; lane==col within each 64-group) +
// register-direct selection. R13 chassis; GEMM inner op forced to
// v_pk_fma_f32 (halves GEMM VALU issue vs the scalarized elementwise_fma).
// Candidate order: chunks ascending, groups g=0..7 ascending, ctz within
// group = global ascending column order -> bit-identical output.
template <bool SEED>
__device__ __forceinline__ void tile_work(const float* __restrict__ bp,
                                          const float* As,
                                          const float* xxb, int m0, int w, int lane,
                                          const float (&xnr)[8],
                                          float (&val)[8], int (&idx)[8],
                                          float (&thd)[8]) {
  float xm[8];
#pragma unroll
  for (int g = 0; g < 8; ++g) xm[g] = xxb[m0 + 64 * g + lane];

  const float* Aw = As + 8 * w;                    // rows 8w..8w+7, LDA=64
  const float* bc = bp + m0;                       // per-lane: col m0+lane

  v2f acc[8][4];                                   // [row][col-pair] = 64 VGPR
#pragma unroll
  for (int r = 0; r < 8; ++r)
#pragma unroll
    for (int gp = 0; gp < 4; ++gp) { acc[r][gp].x = 0.f; acc[r][gp].y = 0.f; }

#pragma unroll 2
  for (int c = 0; c < CH; ++c) {
    float4 A0 = *(const float4*)(Aw + c * 64);       // rows 8w..8w+3 (broadcast)
    float4 A1 = *(const float4*)(Aw + c * 64 + 4);   // rows 8w+4..8w+7
    const float* bcc = bc + (size_t)c * NPTS;
    v2f bb[4];
    bb[0].x = bcc[0];    bb[0].y = bcc[64];          // cols m0+{0,64}+lane
    bb[1].x = bcc[128];  bb[1].y = bcc[192];
    bb[2].x = bcc[256];  bb[2].y = bcc[320];
    bb[3].x = bcc[384];  bb[3].y = bcc[448];
    v2f a01; a01.x = A0.x; a01.y = A0.y;             // natural reg pairs from
    v2f a23; a23.x = A0.z; a23.y = A0.w;             // the b128 load
    v2f a45; a45.x = A1.x; a45.y = A1.y;
    v2f a67; a67.x = A1.z; a67.y = A1.w;
#pragma unroll
    for (int gp = 0; gp < 4; ++gp) {
      fma2pair(a01, bb[gp], acc[0][gp], acc[1][gp]);
      fma2pair(a23, bb[gp], acc[2][gp], acc[3][gp]);
      fma2pair(a45, bb[gp], acc[4][gp], acc[5][gp]);
      fma2pair(a67, bb[gp], acc[6][gp], acc[7][gp]);
    }
  }

#pragma unroll
  for (int r = 0; r < 8; ++r) {
#pragma unroll
    for (int gp = 0; gp < 4; ++gp) {
      float d0 = (2.f * acc[r][gp].x - xnr[r]) - xm[2 * gp];
      if (SEED && gp == 0) {
        seed_sort(d0, lane, val[r], idx[r], thd[r]);  // m0==0, g==0: col==lane
      } else {
        insert_group(d0, m0 + 128 * gp, lane, val[r], idx[r], thd[r]);
      }
      float d1 = (2.f * acc[r][gp].y - xnr[r]) - xm[2 * gp + 1];
      insert_group(d1, m0 + 128 * gp + 64, lane, val[r], idx[r], thd[r]);
    }
  }
}

// ---------------- K1: fused distance-GEMM + register-direct top-20 ----------
// 512 threads = 8 waves; wave w owns rows 8w..8w+7; 64 rows/block.
// Grid = 512 blocks = 2 blocks/CU -> 16 waves/CU = 4 waves/SIMD.
// LDS = As[64][64] 16KB only; B from L2 (XCD swizzle b=bid&7); one barrier.
__launch_bounds__(512, 4)
__global__ void k_knn(const float* __restrict__ x, const float* __restrict__ xx,
                      int* __restrict__ idxout) {
  __shared__ float As[64 * 64];                    // [c][n], LDA=64
  int tid = threadIdx.x;
  int bid = blockIdx.x;
  int b = bid & 7, nb = bid >> 3;                  // XCD-swizzled decode
  int n0 = nb * 64;
  const float* xb = x + (size_t)b * CH * NPTS;
  const float* xxb = xx + b * NPTS;
  int lane = tid & 63;
  int w = tid >> 6;                                // 0..7

  // stage A-tile [c][n]: 4096 floats, 512 threads x 8 floats
  {
    int c = tid >> 3, n8 = (tid & 7) << 3;
    float4 v0 = *(const float4*)(xb + (size_t)c * NPTS + n0 + n8);
    float4 v1 = *(const float4*)(xb + (size_t)c * NPTS + n0 + n8 + 4);
    *(float4*)(As + c * 64 + n8) = v0;
    *(float4*)(As + c * 64 + n8 + 4) = v1;
  }

  float xnr[8];
#pragma unroll
  for (int r = 0; r < 8; ++r) xnr[r] = xxb[n0 + 8 * w + r];

  float val[8]; int idx[8]; float thd[8];
#pragma unroll
  for (int r = 0; r < 8; ++r) { val[r] = NEG_INF; idx[r] = 0; thd[r] = NEG_INF; }

  __syncthreads();                                 // As ready (the ONLY barrier)

  const float* bp = xb + lane;                     // per-lane B base

  // chunk 0: seeded selection
  tile_work<true>(bp, As, xxb, 0, w, lane, xnr, val, idx, thd);

#pragma unroll 1
  for (int mt = 1; mt < NPTS / 512; ++mt)
    tile_work<false>(bp, As, xxb, mt * 512, w, lane, xnr, val, idx, thd);

  // emit: lane l (<20) holds l-th best index for row 8w+r
#pragma unroll
  for (int r = 0; r < 8; ++r) {
    int n = n0 + 8 * w + r;
    if (lane < KNN) idxout[(size_t)(b * NPTS + n) * KNN + lane] = idx[r];
  }
}

// ---------------- K3: gather + max + leaky, transpose to (B,O,N) ----------------
__global__ void k_out(const float* __restrict__ P, const float* __restrict__ Q,
                      const int* __restrict__ idx, float* __restrict__ out) {
  __shared__ float T[64 * 65];
  int tid = threadIdx.x;
  int nb = blockIdx.x, b = blockIdx.y;
  int n0 = nb * 64;
  int o = tid & 63, ng = tid >> 6;
  const float* Pb = P + (size_t)b * NPTS * 64;
  for (int p = 0; p < 16; ++p) {
    int nl = p * 4 + ng;
    int n = n0 + nl;
    const int* ip = idx + (size_t)(b * NPTS + n) * KNN;
    float mx = NEG_INF;
#pragma unroll
    for (int k = 0; k < KNN; ++k) {
      int id = ip[k];
      float v = Pb[(size_t)id * 64 + o];
      mx = fmaxf(mx, v);
    }
    float z = mx + Q[(size_t)(b * NPTS + n) * 64 + o];
    z = (z >= 0.f) ? z : NEG_SLOPE * z;
    T[o * 65 + nl] = z;
  }
  __syncthreads();
  float* ob = out + (size_t)b * 64 * NPTS + n0;
  int nl = tid & 63;
  for (int w = 0; w < 16; ++w) {
    int oo = w * 4 + ng;
    ob[(size_t)oo * NPTS + nl] = T[oo * 65 + nl];
  }
}

extern "C" void kernel_launch(void* const* d_in, const int* in_sizes, int n_in,
                              void* d_out, int out_size, void* d_ws, size_t ws_size,
                              hipStream_t stream) {
  const float* x     = (const float*)d_in[0];
  const float* W     = (const float*)d_in[1];
  const float* gamma = (const float*)d_in[2];
  const float* beta  = (const float*)d_in[3];
  const float* rmean = (const float*)d_in[4];
  const float* rvar  = (const float*)d_in[5];
  float* out = (float*)d_out;

  float* xx = (float*)d_ws;                        // 32768 floats
  float* P  = xx + 32768;                          // 2097152 floats
  float* Q  = P + 2097152;                         // 2097152 floats
  int*   idx = (int*)(Q + 2097152);                // 655360 ints

  k_pq<<<BATCH * NPTS / 16, 256, 0, stream>>>(x, W, gamma, beta, rmean, rvar,
                                              P, Q, xx);
  k_knn<<<BATCH * NPTS / 64, 512, 0, stream>>>(x, xx, idx);
  k_out<<<dim3(NPTS / 64, BATCH), 256, 0, stream>>>(P, Q, idx, out);
}